// Round 1
// baseline (465.559 us; speedup 1.0000x reference)
//
#include <hip/hip_runtime.h>
#include <cstdint>

#define M_DIM 8192
#define K_DIM 4096
#define N_DIM 4096
#define NKT   32     // K-tiles of 128 (= one weight-scale block each)

typedef int   v4i __attribute__((ext_vector_type(4)));
typedef float v4f __attribute__((ext_vector_type(4)));

__device__ __forceinline__ void gload_lds16(const void* g, void* l) {
  __builtin_amdgcn_global_load_lds(
      (const __attribute__((address_space(1))) void*)g,
      (__attribute__((address_space(3))) void*)l, 16, 0, 0);
}

// -------- Kernel 0: repack int32-materialized weights to int8 --------
__global__ __launch_bounds__(256) void pack_w(
    const int* __restrict__ w32, int* __restrict__ w8) {
  const size_t i = (size_t)blockIdx.x * 256 + threadIdx.x;
  const int4 v = ((const int4*)w32)[i];
  w8[i] = (v.x & 255) | ((v.y & 255) << 8) | ((v.z & 255) << 16) | ((v.w & 255) << 24);
}

// ---------------- Kernel 1: per-row dynamic int8 quantization ----------------
__global__ __launch_bounds__(256) void quant_rows(
    const float* __restrict__ x, int8_t* __restrict__ xq, float* __restrict__ xs) {
  const int row = blockIdx.x;
  const int tid = threadIdx.x;
  const float4* xr = (const float4*)(x + (size_t)row * K_DIM);

  float4 v[4];
  float amax = 0.f;
#pragma unroll
  for (int i = 0; i < 4; ++i) {
    v[i] = xr[i * 256 + tid];
    amax = fmaxf(amax, fmaxf(fmaxf(fabsf(v[i].x), fabsf(v[i].y)),
                             fmaxf(fabsf(v[i].z), fabsf(v[i].w))));
  }
#pragma unroll
  for (int off = 32; off > 0; off >>= 1)
    amax = fmaxf(amax, __shfl_xor(amax, off, 64));

  __shared__ float red[4];
  if ((tid & 63) == 0) red[tid >> 6] = amax;
  __syncthreads();
  amax = fmaxf(fmaxf(red[0], red[1]), fmaxf(red[2], red[3]));
  amax = fmaxf(amax, 1e-6f);
  const float s   = amax / 127.0f;
  const float inv = 127.0f / amax;
  if (tid == 0) xs[row] = s;

  int* xqo = (int*)(xq + (size_t)row * K_DIM);
#pragma unroll
  for (int i = 0; i < 4; ++i) {
    int q0 = (int)fminf(fmaxf(rintf(v[i].x * inv), -128.f), 127.f);
    int q1 = (int)fminf(fmaxf(rintf(v[i].y * inv), -128.f), 127.f);
    int q2 = (int)fminf(fmaxf(rintf(v[i].z * inv), -128.f), 127.f);
    int q3 = (int)fminf(fmaxf(rintf(v[i].w * inv), -128.f), 127.f);
    xqo[i * 256 + tid] =
        (q0 & 255) | ((q1 & 255) << 8) | ((q2 & 255) << 16) | ((q3 & 255) << 24);
  }
}

// ---------------- Kernel 2: int8 block-scaled GEMM, 256x256 8-phase ----------
// Port of the 256-square 8-phase template (T3+T4+T5) to int8 with per-K-block
// dequant. 8 waves (2M x 4N), each owns a 128x64 output region as 8x4 tiles of
// mfma_i32_16x16x64_i8. BK = 128 int8 = one weight-scale block, so the int32
// accumulator spans exactly one scale block before cvt+fma into fp32.
// LDS: 2 x (A 32KB + B 32KB) = 128 KiB double buffer -> 1 block/CU, 2 waves/SIMD.
// Per K-tile: 4 phases; phase q computes C-quadrant q (2 tile-rows x 4 tile-cols
// x K=128 -> 16 MFMA) after 12 ds_read_b128 (4 A + 8 B frags). Next tile's
// staging (8 global_load_lds / thread) is issued in phases 0-1 and drained with
// a single vmcnt(0) at the end of phase 3 -> >=2 phases of MFMA hide the load
// latency (vs. the old 2-barrier loop's zero-slack drain = the 28% MfmaUtil cap).
// Chunk-XOR swizzle (chunk c of row r at slot c^(r&7)) keeps ds_read_b128
// conflict-free (measured 0) while global_load_lds stays lane-linear:
// source chunk is pre-swizzled, (row+64)&7 == row&7 so rounds are invariant.
__global__ __launch_bounds__(512, 2) void gemm_q8(
    const int8_t* __restrict__ xq, const int8_t* __restrict__ wq,
    const float* __restrict__ wscale, const float* __restrict__ xs,
    const float* __restrict__ bias, float* __restrict__ out) {
  __shared__ int8_t lA[2][32768];  // [buf][row 0..255][128B], swizzled
  __shared__ int8_t lB[2][32768];

  const int tid = threadIdx.x;
  const int m0 = blockIdx.x * 256;
  const int n0 = blockIdx.y * 256;

  // staging map: thread t -> row t>>3 (+64/round, +128/half), slot t&7,
  // pre-swizzled global chunk (t&7)^(row&7)
  const int srow   = tid >> 3;
  const int schunk = (tid & 7) ^ (srow & 7);
  const int8_t* ga = xq + (size_t)(m0 + srow) * K_DIM + schunk * 16;
  const int8_t* gb = wq + (size_t)(n0 + srow) * K_DIM + schunk * 16;

  const int lane = tid & 63;
  const int wv = tid >> 6;
  const int wm = (wv >> 2) << 7;  // wave m-offset: 0/128
  const int wn = (wv & 3) << 6;   // wave n-offset: 0/64/128/192
  const int lr = lane & 15;
  const int lq = lane >> 4;

  // fragment byte offsets within a row: k-half h, quad lq -> chunk h*4+lq,
  // swizzled by row&7 == lr&7 (tile-row offsets are multiples of 16)
  const int swz0 = ((lq ^ (lr & 7)) << 4);
  const int swz1 = (((4 | lq) ^ (lr & 7)) << 4);
  const int arow = (wm + lr) << 7;  // *128 B/row
  const int brow = (wn + lr) << 7;

  v4f facc[8][4];
#pragma unroll
  for (int i = 0; i < 8; ++i)
#pragma unroll
    for (int j = 0; j < 4; ++j) facc[i][j] = {0.f, 0.f, 0.f, 0.f};

  const float* wsp = wscale + n0 + wn + lr;  // + kt*N + j*16

  // prologue: stage tile 0 into buf 0 (8 loads/thread), drain, barrier
#pragma unroll
  for (int h = 0; h < 2; ++h)
#pragma unroll
    for (int p = 0; p < 2; ++p) {
      const size_t go = (size_t)(h * 128 + p * 64) * K_DIM;
      const int lo = h * 16384 + p * 8192 + tid * 16;
      gload_lds16(ga + go, &lA[0][lo]);
      gload_lds16(gb + go, &lB[0][lo]);
    }
  asm volatile("s_waitcnt vmcnt(0)" ::: "memory");
  __builtin_amdgcn_s_barrier();

  for (int kt = 0; kt < NKT; ++kt) {
    const int d = kt & 1;
    const int kn = (kt + 1) & (NKT - 1);  // last iter re-stages tile 0: harmless
    const int8_t* gan = ga + (size_t)kn * 128;
    const int8_t* gbn = gb + (size_t)kn * 128;
    int8_t* lan = &lA[d ^ 1][0];
    int8_t* lbn = &lB[d ^ 1][0];
    const int8_t* pa0 = &lA[d][arow + swz0];
    const int8_t* pa1 = &lA[d][arow + swz1];
    const int8_t* pb0 = &lB[d][brow + swz0];
    const int8_t* pb1 = &lB[d][brow + swz1];

    // this tile's 4 column scales (issued early; first use after phase-0 MFMAs)
    float wsv[4];
#pragma unroll
    for (int j = 0; j < 4; ++j) wsv[j] = wsp[(size_t)kt * N_DIM + j * 16];

#pragma unroll
    for (int q = 0; q < 4; ++q) {
      // 12 ds_read_b128: A frags for quadrant q (2 tile-rows x 2 k-halves),
      // B frags (4 tile-cols x 2 k-halves)
      v4i af[2][2], bf[4][2];
#pragma unroll
      for (int ii = 0; ii < 2; ++ii) {
        af[ii][0] = *(const v4i*)(pa0 + (q * 2 + ii) * 2048);
        af[ii][1] = *(const v4i*)(pa1 + (q * 2 + ii) * 2048);
      }
#pragma unroll
      for (int j = 0; j < 4; ++j) {
        bf[j][0] = *(const v4i*)(pb0 + j * 2048);
        bf[j][1] = *(const v4i*)(pb1 + j * 2048);
      }

      // stage next tile: half h=q in phases 0/1 (4 loads each), none in 2/3
      if (q < 2) {
#pragma unroll
        for (int p = 0; p < 2; ++p) {
          const size_t go = (size_t)(q * 128 + p * 64) * K_DIM;
          const int lo = q * 16384 + p * 8192 + tid * 16;
          gload_lds16(gan + go, lan + lo);
          gload_lds16(gbn + go, lbn + lo);
        }
      }

      __builtin_amdgcn_s_barrier();
      asm volatile("s_waitcnt lgkmcnt(0)" ::: "memory");
      __builtin_amdgcn_sched_barrier(0);

      __builtin_amdgcn_s_setprio(1);
      v4i ic[2][4];
#pragma unroll
      for (int ii = 0; ii < 2; ++ii)
#pragma unroll
        for (int j = 0; j < 4; ++j) {
          ic[ii][j] = {0, 0, 0, 0};
          ic[ii][j] = __builtin_amdgcn_mfma_i32_16x16x64_i8(af[ii][0], bf[j][0], ic[ii][j], 0, 0, 0);
          ic[ii][j] = __builtin_amdgcn_mfma_i32_16x16x64_i8(af[ii][1], bf[j][1], ic[ii][j], 0, 0, 0);
        }
      __builtin_amdgcn_s_setprio(0);

      // per-block dequant: one cvt+fma per acc elem (scale depends on col only)
#pragma unroll
      for (int ii = 0; ii < 2; ++ii)
#pragma unroll
        for (int j = 0; j < 4; ++j)
#pragma unroll
          for (int r = 0; r < 4; ++r)
            facc[q * 2 + ii][j][r] += wsv[j] * (float)ic[ii][j][r];

      if (q == 3) {
        // drain next-tile staging; last issue was 2 phases ago -> near-zero stall
        asm volatile("s_waitcnt vmcnt(0)" ::: "memory");
        __builtin_amdgcn_sched_barrier(0);
      }
      __builtin_amdgcn_s_barrier();
    }
  }

  // epilogue: out[m,n] = facc * xs[m] + bias[n]
  float bv[4];
#pragma unroll
  for (int j = 0; j < 4; ++j) bv[j] = bias[n0 + wn + j * 16 + lr];
#pragma unroll
  for (int i = 0; i < 8; ++i) {
    const int mb = m0 + wm + i * 16 + (lq << 2);
#pragma unroll
    for (int r = 0; r < 4; ++r) {
      const float sc = xs[mb + r];
      float* op = out + (size_t)(mb + r) * N_DIM + n0 + wn + lr;
#pragma unroll
      for (int j = 0; j < 4; ++j) op[j * 16] = facc[i][j][r] * sc + bv[j];
    }
  }
}

extern "C" void kernel_launch(void* const* d_in, const int* in_sizes, int n_in,
                              void* d_out, int out_size, void* d_ws, size_t ws_size,
                              hipStream_t stream) {
  const float* x      = (const float*)d_in[0];
  const int*   w32    = (const int*)d_in[1];
  const float* wscale = (const float*)d_in[2];
  const float* bias   = (const float*)d_in[3];
  float* out = (float*)d_out;

  int8_t* xq  = (int8_t*)d_ws;
  int8_t* wq8 = (int8_t*)d_ws + (size_t)M_DIM * K_DIM;
  float*  xs  = (float*)((char*)d_ws + (size_t)M_DIM * K_DIM + (size_t)N_DIM * K_DIM);

  pack_w<<<(N_DIM * (size_t)K_DIM / 4 + 255) / 256, 256, 0, stream>>>(w32, (int*)wq8);
  quant_rows<<<M_DIM, 256, 0, stream>>>(x, xq, xs);
  dim3 grid(M_DIM / 256, N_DIM / 256);
  gemm_q8<<<grid, 512, 0, stream>>>(xq, wq8, wscale, xs, bias, out);
}

// Round 2
// 439.999 us; speedup vs baseline: 1.0581x; 1.0581x over previous
//
#include <hip/hip_runtime.h>
#include <cstdint>

#define M_DIM 8192
#define K_DIM 4096
#define N_DIM 4096
#define NKT   32     // K-tiles of 128 (= one weight-scale block each)

typedef int   v4i  __attribute__((ext_vector_type(4)));
typedef int   v16i __attribute__((ext_vector_type(16)));
typedef float v4f  __attribute__((ext_vector_type(4)));

__device__ __forceinline__ void gload_lds16(const void* g, void* l) {
  __builtin_amdgcn_global_load_lds(
      (const __attribute__((address_space(1))) void*)g,
      (__attribute__((address_space(3))) void*)l, 16, 0, 0);
}

// -------- Kernel 0: repack int32-materialized weights to int8 --------
__global__ __launch_bounds__(256) void pack_w(
    const int* __restrict__ w32, int* __restrict__ w8) {
  const size_t i = (size_t)blockIdx.x * 256 + threadIdx.x;
  const int4 v = ((const int4*)w32)[i];
  w8[i] = (v.x & 255) | ((v.y & 255) << 8) | ((v.z & 255) << 16) | ((v.w & 255) << 24);
}

// ---------------- Kernel 1: per-row dynamic int8 quantization ----------------
__global__ __launch_bounds__(256) void quant_rows(
    const float* __restrict__ x, int8_t* __restrict__ xq, float* __restrict__ xs) {
  const int row = blockIdx.x;
  const int tid = threadIdx.x;
  const float4* xr = (const float4*)(x + (size_t)row * K_DIM);

  float4 v[4];
  float amax = 0.f;
#pragma unroll
  for (int i = 0; i < 4; ++i) {
    v[i] = xr[i * 256 + tid];
    amax = fmaxf(amax, fmaxf(fmaxf(fabsf(v[i].x), fabsf(v[i].y)),
                             fmaxf(fabsf(v[i].z), fabsf(v[i].w))));
  }
#pragma unroll
  for (int off = 32; off > 0; off >>= 1)
    amax = fmaxf(amax, __shfl_xor(amax, off, 64));

  __shared__ float red[4];
  if ((tid & 63) == 0) red[tid >> 6] = amax;
  __syncthreads();
  amax = fmaxf(fmaxf(red[0], red[1]), fmaxf(red[2], red[3]));
  amax = fmaxf(amax, 1e-6f);
  const float s   = amax / 127.0f;
  const float inv = 127.0f / amax;
  if (tid == 0) xs[row] = s;

  int* xqo = (int*)(xq + (size_t)row * K_DIM);
#pragma unroll
  for (int i = 0; i < 4; ++i) {
    int q0 = (int)fminf(fmaxf(rintf(v[i].x * inv), -128.f), 127.f);
    int q1 = (int)fminf(fmaxf(rintf(v[i].y * inv), -128.f), 127.f);
    int q2 = (int)fminf(fmaxf(rintf(v[i].z * inv), -128.f), 127.f);
    int q3 = (int)fminf(fmaxf(rintf(v[i].w * inv), -128.f), 127.f);
    xqo[i * 256 + tid] =
        (q0 & 255) | ((q1 & 255) << 8) | ((q2 & 255) << 16) | ((q3 & 255) << 24);
  }
}

// ---------------- Kernel 2: int8 block-scaled GEMM, 256x256, k-slice phases --
// R1 post-mortem: quadrant-phase structure re-read B 4x (48 ds_read/wave/ktile)
// and put 8 barrier-locked dequant tails per K-tile on the critical path ->
// MfmaUtil stuck at 26%. This version phases over K-SLICES covering all output
// tiles: every fragment is read once (24 ds_read/wave/ktile, LDS pipe ~1700 cyc
// < MFMA floor 2612), and there is ONE barrier per K-tile. 32x32x32 i8 MFMA
// halves instruction count. Dequant (per-mtile, 32 elems) sits between
// independent MFMA clusters, off the barrier path; free-running waves within
// the K-tile overlap one wave's dequant with the other's MFMA (m114 regime).
// Staging for tile kt+1 is issued before the i-loop and drained by the
// __syncthreads() at tile end: ~2600 cyc of slack vs ~900 cyc HBM latency,
// so the m97 zero-slack vmcnt(0) stall is structurally gone with only one
// barrier. Chunk-XOR swizzle as before (0 measured conflicts).
// Wave = 128x64 output = 4(m) x 2(n) tiles of 32x32.
// Regs: facc 128 + bfr 32 + a cur/nxt 32 + ic 32 + addr ~20 = ~244 <= 256.
__global__ __launch_bounds__(512, 2) void gemm_q8(
    const int8_t* __restrict__ xq, const int8_t* __restrict__ wq,
    const float* __restrict__ wscale, const float* __restrict__ xs,
    const float* __restrict__ bias, float* __restrict__ out) {
  __shared__ int8_t lA[2][32768];  // [buf][row 0..255][128B], chunk-swizzled
  __shared__ int8_t lB[2][32768];

  const int tid = threadIdx.x;
  const int m0 = blockIdx.x * 256;
  const int n0 = blockIdx.y * 256;

  // staging map: thread t -> row t>>3 (+64/round, +128/half), slot t&7,
  // pre-swizzled global chunk (t&7)^(row&7); (row+64)&7==row&7 so invariant.
  const int srow   = tid >> 3;
  const int schunk = (tid & 7) ^ (srow & 7);
  const int8_t* ga = xq + (size_t)(m0 + srow) * K_DIM + schunk * 16;
  const int8_t* gb = wq + (size_t)(n0 + srow) * K_DIM + schunk * 16;

  const int lane = tid & 63;
  const int wv  = tid >> 6;
  const int wm  = (wv >> 2) << 7;  // wave m-offset: 0/128
  const int wn  = (wv & 3) << 6;   // wave n-offset: 0/64/128/192
  const int l31 = lane & 31;
  const int hi  = lane >> 5;

  // fragment chunk swizzle: kstep k, half hi -> chunk 2k+hi, XOR row&7(=lane&7)
  int swz[4];
#pragma unroll
  for (int k = 0; k < 4; ++k) swz[k] = (((2 * k + hi) ^ (lane & 7)) << 4);
  const int aoff = (wm + l31) << 7;  // A row byte offset (row*128)
  const int boff = (wn + l31) << 7;  // B row byte offset

  float facc[4][2][16];
#pragma unroll
  for (int i = 0; i < 4; ++i)
#pragma unroll
    for (int j = 0; j < 2; ++j)
#pragma unroll
      for (int r = 0; r < 16; ++r) facc[i][j][r] = 0.f;

  const float* wsp = wscale + n0 + wn + l31;  // + kt*N, + 32 for j=1

  // prologue: stage tile 0 into buf 0 (8 loads/thread), drain, barrier
#pragma unroll
  for (int h = 0; h < 2; ++h)
#pragma unroll
    for (int p = 0; p < 2; ++p) {
      const size_t go = (size_t)(h * 128 + p * 64) * K_DIM;
      const int lo = h * 16384 + p * 8192 + tid * 16;
      gload_lds16(ga + go, &lA[0][lo]);
      gload_lds16(gb + go, &lB[0][lo]);
    }
  __syncthreads();

  for (int kt = 0; kt < NKT; ++kt) {
    const int d = kt & 1;
    const int kn = (kt + 1) & (NKT - 1);  // last iter re-stages tile 0: harmless
    const int8_t* gan = ga + (size_t)kn * 128;
    const int8_t* gbn = gb + (size_t)kn * 128;
    int8_t* lan = &lA[d ^ 1][0];
    int8_t* lbn = &lB[d ^ 1][0];
    const int8_t* pa = &lA[d][0];
    const int8_t* pb = &lB[d][0];

    // this tile's 2 column scales (compiler inserts the counted vmcnt for use)
    const float ws0 = wsp[(size_t)kt * N_DIM];
    const float ws1 = wsp[(size_t)kt * N_DIM + 32];

    // B fragments: read once, held for the whole K-tile (32 VGPRs)
    v4i bfr[2][4];
#pragma unroll
    for (int j = 0; j < 2; ++j)
#pragma unroll
      for (int k = 0; k < 4; ++k)
        bfr[j][k] = *(const v4i*)(pb + boff + j * 4096 + swz[k]);

    // A fragments for mtile 0
    v4i acur[4];
#pragma unroll
    for (int k = 0; k < 4; ++k)
      acur[k] = *(const v4i*)(pa + aoff + swz[k]);

    // issue next-tile staging now; drained by tile-end __syncthreads (huge slack)
#pragma unroll
    for (int h = 0; h < 2; ++h)
#pragma unroll
      for (int p = 0; p < 2; ++p) {
        const size_t go = (size_t)(h * 128 + p * 64) * K_DIM;
        const int lo = h * 16384 + p * 8192 + tid * 16;
        gload_lds16(gan + go, lan + lo);
        gload_lds16(gbn + go, lbn + lo);
      }

#pragma unroll
    for (int i = 0; i < 4; ++i) {
      // software-pipeline next mtile's A reads above this mtile's MFMA/dequant
      v4i anxt[4];
      if (i < 3) {
#pragma unroll
        for (int k = 0; k < 4; ++k)
          anxt[k] = *(const v4i*)(pa + aoff + (i + 1) * 4096 + swz[k]);
      }

      v16i ic0 = {};
      v16i ic1 = {};
      __builtin_amdgcn_s_setprio(1);
#pragma unroll
      for (int k = 0; k < 4; ++k) {
        ic0 = __builtin_amdgcn_mfma_i32_32x32x32_i8(acur[k], bfr[0][k], ic0, 0, 0, 0);
        ic1 = __builtin_amdgcn_mfma_i32_32x32x32_i8(acur[k], bfr[1][k], ic1, 0, 0, 0);
      }
      __builtin_amdgcn_s_setprio(0);

      // per-block dequant: 32 cvt+fma, scale depends on column only
#pragma unroll
      for (int r = 0; r < 16; ++r) facc[i][0][r] += ws0 * (float)ic0[r];
#pragma unroll
      for (int r = 0; r < 16; ++r) facc[i][1][r] += ws1 * (float)ic1[r];

      if (i < 3) {
#pragma unroll
        for (int k = 0; k < 4; ++k) acur[k] = anxt[k];
      }
    }

    __syncthreads();  // drains lgkm + vmcnt (staging) and barriers: 1 per K-tile
  }

  // epilogue: out[m,n] = facc * xs[m] + bias[n]
  // 32x32 C layout: row = (r&3) + 8*(r>>2) + 4*hi, col = l31
  const float bv0 = bias[n0 + wn + l31];
  const float bv1 = bias[n0 + wn + 32 + l31];
#pragma unroll
  for (int i = 0; i < 4; ++i) {
    const int rbase = m0 + wm + i * 32 + (hi << 2);
#pragma unroll
    for (int q = 0; q < 4; ++q) {
      const v4f xv = *(const v4f*)(xs + rbase + q * 8);
#pragma unroll
      for (int r4 = 0; r4 < 4; ++r4) {
        const int r = q * 4 + r4;
        float* op = out + (size_t)(rbase + q * 8 + r4) * N_DIM + n0 + wn + l31;
        op[0]  = facc[i][0][r] * xv[r4] + bv0;
        op[32] = facc[i][1][r] * xv[r4] + bv1;
      }
    }
  }
}

extern "C" void kernel_launch(void* const* d_in, const int* in_sizes, int n_in,
                              void* d_out, int out_size, void* d_ws, size_t ws_size,
                              hipStream_t stream) {
  const float* x      = (const float*)d_in[0];
  const int*   w32    = (const int*)d_in[1];
  const float* wscale = (const float*)d_in[2];
  const float* bias   = (const float*)d_in[3];
  float* out = (float*)d_out;

  int8_t* xq  = (int8_t*)d_ws;
  int8_t* wq8 = (int8_t*)d_ws + (size_t)M_DIM * K_DIM;
  float*  xs  = (float*)((char*)d_ws + (size_t)M_DIM * K_DIM + (size_t)N_DIM * K_DIM);

  pack_w<<<(N_DIM * (size_t)K_DIM / 4 + 255) / 256, 256, 0, stream>>>(w32, (int*)wq8);
  quant_rows<<<M_DIM, 256, 0, stream>>>(x, xq, xs);
  dim3 grid(M_DIM / 256, N_DIM / 256);
  gemm_q8<<<grid, 512, 0, stream>>>(xq, wq8, wscale, xs, bias, out);
}